// Round 6
// baseline (385.327 us; speedup 1.0000x reference)
//
#include <hip/hip_runtime.h>
#include <hip/hip_bf16.h>

#define D_MODEL 1024
#define NH 16
#define DK 64
#define S_LEN 2048
#define BATCH 2
#define M_ROWS (BATCH * S_LEN)   // 4096

typedef float    floatx4 __attribute__((ext_vector_type(4)));
typedef _Float16 half8   __attribute__((ext_vector_type(8)));
typedef _Float16 half4v  __attribute__((ext_vector_type(4)));
typedef _Float16 half2v  __attribute__((ext_vector_type(2)));

#define LOG2E 1.4426950408889634f

__device__ __forceinline__ half8 ldh8(const _Float16* p) {
    return __builtin_bit_cast(half8, *(const uint4*)p);
}
__device__ __forceinline__ void gld16(const void* g, void* l) {
    __builtin_amdgcn_global_load_lds(
        (const __attribute__((address_space(1))) void*)g,
        (__attribute__((address_space(3))) void*)l, 16, 0, 0);
}
// swap lanes 0<->1, 2<->3 within each quad (DPP quad_perm(1,0,3,2))
__device__ __forceinline__ float dpp_swap1(float x) {
    return __builtin_bit_cast(float,
        __builtin_amdgcn_mov_dpp(__builtin_bit_cast(int, x), 0xB1, 0xF, 0xF, false));
}

// ---------------------------------------------------------------------------
// fp32 [R][1024] -> fp16 [R][1024].  grid (R, Z); Z selects src / dst slice.
// ---------------------------------------------------------------------------
__global__ __launch_bounds__(256)
void cast_h(const float* __restrict__ s0, const float* __restrict__ s1,
            const float* __restrict__ s2, const float* __restrict__ s3,
            _Float16* __restrict__ out, int R) {
    const int z = blockIdx.y;
    const float* src = (z == 0) ? s0 : (z == 1) ? s1 : (z == 2) ? s2 : s3;
    const size_t idx = ((size_t)blockIdx.x * 256 + threadIdx.x) * 4;
    float4 v = *(const float4*)&src[idx];
    half4v h = {(_Float16)v.x, (_Float16)v.y, (_Float16)v.z, (_Float16)v.w};
    *(half4v*)&out[(size_t)z * R * 1024 + idx] = h;
}

// ---------------------------------------------------------------------------
// C = A[M,1024] @ W[1024,1024]^T (+bias), fp16 MFMA.  (validated round 4)
// OUTMODE 0: fp32 row-major.  OUTMODE 1: fp16 head-major, z selects problem;
// z==0 (Q) scaled by 0.125*log2e (exp2-folding for attention).
// ---------------------------------------------------------------------------
template <int OUTMODE>
__global__ __launch_bounds__(256)
void gemm_f16(const _Float16* __restrict__ Abase, const _Float16* __restrict__ Wbase,
              const float* __restrict__ b0, const float* __restrict__ b1,
              const float* __restrict__ b2, void* __restrict__ Obase) {
    __shared__ __align__(16) _Float16 As[128 * 64];
    __shared__ __align__(16) _Float16 Ws[128 * 64];
    const int tid = threadIdx.x;
    const int w = tid >> 6, lane = tid & 63;
    const int l15 = lane & 15, q4 = lane >> 4;
    const int z = (OUTMODE == 1) ? blockIdx.z : 0;
    const int m0 = blockIdx.y * 128, n0 = blockIdx.x * 128;
    const int wm = w >> 1, wn = w & 1;

    const _Float16* A = Abase + (size_t)z * M_ROWS * 1024;
    const _Float16* W = Wbase + (size_t)z * 1024 * 1024;
    const float* bias = (OUTMODE == 1) ? ((z == 0) ? b0 : (z == 1) ? b1 : b2) : b0;

    int srow[4], sseg[4];
#pragma unroll
    for (int i = 0; i < 4; i++) {
        const int slot = i * 256 + tid;
        srow[i] = slot >> 3;
        sseg[i] = ((slot & 7) ^ (srow[i] & 7)) * 8;
    }

    int aoff[4][2], woff[4][2];
#pragma unroll
    for (int r = 0; r < 4; r++) {
        const int ar = wm * 64 + r * 16 + l15;
        const int wr = wn * 64 + r * 16 + l15;
#pragma unroll
        for (int kc = 0; kc < 2; kc++) {
            aoff[r][kc] = (ar * 8 + ((kc * 4 + q4) ^ (ar & 7))) * 8;
            woff[r][kc] = (wr * 8 + ((kc * 4 + q4) ^ (wr & 7))) * 8;
        }
    }

    floatx4 acc[4][4];
#pragma unroll
    for (int r = 0; r < 4; r++)
#pragma unroll
        for (int c = 0; c < 4; c++) acc[r][c] = (floatx4){0.f, 0.f, 0.f, 0.f};

    for (int k0 = 0; k0 < 1024; k0 += 64) {
#pragma unroll
        for (int i = 0; i < 4; i++) {
            const int lb = (i * 256 + w * 64) * 8;
            gld16(&A[(size_t)(m0 + srow[i]) * 1024 + k0 + sseg[i]], &As[lb]);
            gld16(&W[(size_t)(n0 + srow[i]) * 1024 + k0 + sseg[i]], &Ws[lb]);
        }
        __syncthreads();

        half8 af[4][2], wf[4][2];
#pragma unroll
        for (int r = 0; r < 4; r++)
#pragma unroll
            for (int kc = 0; kc < 2; kc++) {
                af[r][kc] = ldh8(&As[aoff[r][kc]]);
                wf[r][kc] = ldh8(&Ws[woff[r][kc]]);
            }
#pragma unroll
        for (int kc = 0; kc < 2; kc++)
#pragma unroll
            for (int r = 0; r < 4; r++)
#pragma unroll
                for (int c = 0; c < 4; c++)
                    acc[r][c] = __builtin_amdgcn_mfma_f32_16x16x32_f16(
                        af[r][kc], wf[c][kc], acc[r][c], 0, 0, 0);
        __syncthreads();
    }

#pragma unroll
    for (int r = 0; r < 4; r++)
#pragma unroll
        for (int c = 0; c < 4; c++)
#pragma unroll
            for (int reg = 0; reg < 4; reg++) {
                const int m = m0 + wm * 64 + r * 16 + q4 * 4 + reg;
                const int n = n0 + wn * 64 + c * 16 + l15;
                float val = acc[r][c][reg] + bias[n];
                if (OUTMODE == 0) {
                    ((float*)Obase)[(size_t)m * 1024 + n] = val;
                } else {
                    if (z == 0) val *= 0.125f * LOG2E;   // 1/sqrt(dk) * log2e
                    const int b = m >> 11, s = m & 2047;
                    const int h = n >> 6, d = n & 63;
                    _Float16* Oz = (_Float16*)Obase + (size_t)z * M_ROWS * 1024;
                    Oz[(((size_t)(b * 16 + h) * S_LEN + s) << 6) + d] = (_Float16)val;
                }
            }
}

// ---------------------------------------------------------------------------
// Vh fp16 [bh][s][64] -> Vt fp16 [bh][d][s]
// ---------------------------------------------------------------------------
__global__ __launch_bounds__(256)
void vt_trans(const short* __restrict__ Vh, short* __restrict__ Vt) {
    __shared__ __align__(16) short T[64][80];
    const int bh = blockIdx.y;
    const int s0 = blockIdx.x * 64;
    const int t = threadIdx.x;
#pragma unroll
    for (int i = 0; i < 2; i++) {
        const int p = t + i * 256, r = p >> 3, c8 = (p & 7) * 8;
        uint4 raw = *(const uint4*)&Vh[((size_t)bh * S_LEN + s0 + r) * 64 + c8];
        const short* sv = (const short*)&raw;
#pragma unroll
        for (int j = 0; j < 8; j++) T[c8 + j][r] = sv[j];
    }
    __syncthreads();
#pragma unroll
    for (int i = 0; i < 2; i++) {
        const int p = t + i * 256, d = p >> 3, seg = (p & 7) * 8;
        *(uint4*)&Vt[((size_t)bh * DK + d) * S_LEN + s0 + seg] =
            *(const uint4*)&T[d][seg];
    }
}

// ---------------------------------------------------------------------------
// mask int32 [S,S] -> bitmask uint64 mb[row][wid]  (row-major, round-4 layout)
// ---------------------------------------------------------------------------
__global__ __launch_bounds__(256)
void mask_pack(const int* __restrict__ mask, unsigned long long* __restrict__ mb) {
    const int gw = blockIdx.x * 4 + (threadIdx.x >> 6);
    const int lane = threadIdx.x & 63;
    const int row = gw >> 5, wid = gw & 31;
    const int mv = mask[(size_t)row * S_LEN + wid * 64 + lane];
    unsigned long long bal = __ballot(mv != 0);
    if (lane == 0) mb[gw] = bal;
}

// ---------------------------------------------------------------------------
// MFMA flash attention, barrier-free streaming version.
// - K/V fragments read DIRECTLY from global (L1/L2-resident tiles): no K/V
//   LDS staging, no __syncthreads anywhere.
// - wave owns 32 q rows (2 subtiles of 16): each K/V frag feeds 2 MFMAs.
// - P routes through per-wave LDS (m120-verified C->A transform), written as
//   packed half2 (DPP pair-swap + cvt_pkrtz): conflict-free ds_write_b32.
// - exp2-folded scores (Q pre-scaled by 0.125*log2e; masked -> -log2e).
// Grid (S/128, B*H), 256 threads = 4 waves.
// ---------------------------------------------------------------------------
__global__ __launch_bounds__(256)
void attn_mfma(const _Float16* __restrict__ Qh, const _Float16* __restrict__ Kh,
               const _Float16* __restrict__ Vt, const unsigned long long* __restrict__ mb,
               _Float16* __restrict__ Xh) {
    __shared__ __align__(16) _Float16 Ps[4][32 * 72];   // per-wave P, 18.4 KB

    const int tid = threadIdx.x;
    const int w = tid >> 6, lane = tid & 63;
    const int l15 = lane & 15, q4 = lane >> 4;
    const int bh = blockIdx.y, b = bh >> 4, h = bh & 15;
    const int qb = blockIdx.x * 128 + w * 32;

    const _Float16* Qg = Qh + ((size_t)bh * S_LEN + qb) * DK;
    const _Float16* Kg = Kh + (size_t)bh * S_LEN * DK;
    const _Float16* Vg = Vt + (size_t)bh * DK * S_LEN;

    // Q fragments (A-operand), resident all kernel.  Scale pre-folded.
    half8 Aq[2][2];
#pragma unroll
    for (int qs = 0; qs < 2; qs++)
#pragma unroll
        for (int ch = 0; ch < 2; ch++)
            Aq[qs][ch] = ldh8(&Qg[(qs * 16 + l15) * DK + ch * 32 + q4 * 8]);

    int mrow[2][4];
#pragma unroll
    for (int qs = 0; qs < 2; qs++)
#pragma unroll
        for (int reg = 0; reg < 4; reg++)
            mrow[qs][reg] = (qb + qs * 16 + q4 * 4 + reg) * (S_LEN / 64);

    floatx4 O[2][4];
#pragma unroll
    for (int qs = 0; qs < 2; qs++)
#pragma unroll
        for (int nt = 0; nt < 4; nt++) O[qs][nt] = (floatx4){0.f, 0.f, 0.f, 0.f};
    float lsum[2][4] = {{0.f, 0.f, 0.f, 0.f}, {0.f, 0.f, 0.f, 0.f}};

    const bool evenlane = ((lane & 1) == 0);

    for (int j0 = 0; j0 < S_LEN; j0 += 64) {
        // K fragments (B-operand of S): K[j0+jt*16+l15][d]
        half8 Kf[4][2];
#pragma unroll
        for (int jt = 0; jt < 4; jt++)
#pragma unroll
            for (int ch = 0; ch < 2; ch++)
                Kf[jt][ch] = ldh8(&Kg[(size_t)(j0 + jt * 16 + l15) * DK +
                                      ch * 32 + q4 * 8]);
        // V^T fragments (B-operand of PV): V^T[nt*16+l15][j0+...]
        half8 bv[4][2];
#pragma unroll
        for (int nt = 0; nt < 4; nt++)
#pragma unroll
            for (int ch = 0; ch < 2; ch++)
                bv[nt][ch] = ldh8(&Vg[(size_t)(nt * 16 + l15) * S_LEN + j0 +
                                      ch * 32 + q4 * 8]);
        const int jw = j0 >> 6;

#pragma unroll
        for (int qs = 0; qs < 2; qs++) {
            // S tile: lane holds S[q=q4*4+reg][key=jt*16+l15] (exp2 domain)
            floatx4 Sf[4];
#pragma unroll
            for (int jt = 0; jt < 4; jt++) {
                floatx4 c = (floatx4){0.f, 0.f, 0.f, 0.f};
                c = __builtin_amdgcn_mfma_f32_16x16x32_f16(Aq[qs][0], Kf[jt][0], c, 0, 0, 0);
                c = __builtin_amdgcn_mfma_f32_16x16x32_f16(Aq[qs][1], Kf[jt][1], c, 0, 0, 0);
                Sf[jt] = c;
            }
            // mask (-1.0 soft mask -> -log2e), exp2, pair-pack, LDS write
#pragma unroll
            for (int reg = 0; reg < 4; reg++) {
                const unsigned long long m = mb[mrow[qs][reg] + jw];
#pragma unroll
                for (int jt = 0; jt < 4; jt++) {
                    float s = Sf[jt][reg];
                    s = ((m >> (jt * 16 + l15)) & 1ull) ? s : -LOG2E;
                    const float p = __builtin_amdgcn_exp2f(s);
                    lsum[qs][reg] += p;
                    const float po = dpp_swap1(p);
                    if (evenlane) {
                        *(unsigned*)&Ps[w][(qs * 16 + q4 * 4 + reg) * 72 +
                                           jt * 16 + l15] =
                            __builtin_bit_cast(unsigned,
                                __builtin_amdgcn_cvt_pkrtz(p, po));
                    }
                }
            }
        }

        // PV: O[qs] += P[qs] @ V   (same-wave LDS write->read, no barrier)
#pragma unroll
        for (int qs = 0; qs < 2; qs++) {
            half8 Ap[2];
#pragma unroll
            for (int ch = 0; ch < 2; ch++)
                Ap[ch] = ldh8(&Ps[w][(qs * 16 + l15) * 72 + ch * 32 + q4 * 8]);
#pragma unroll
            for (int nt = 0; nt < 4; nt++) {
                O[qs][nt] = __builtin_amdgcn_mfma_f32_16x16x32_f16(
                    Ap[0], bv[nt][0], O[qs][nt], 0, 0, 0);
                O[qs][nt] = __builtin_amdgcn_mfma_f32_16x16x32_f16(
                    Ap[1], bv[nt][1], O[qs][nt], 0, 0, 0);
            }
        }
    }

    // reduce row sums over the 16 column-lanes, normalize, store fp16 X
#pragma unroll
    for (int qs = 0; qs < 2; qs++)
#pragma unroll
        for (int reg = 0; reg < 4; reg++) {
#pragma unroll
            for (int off = 1; off < 16; off <<= 1)
                lsum[qs][reg] += __shfl_xor(lsum[qs][reg], off, 64);
        }
#pragma unroll
    for (int qs = 0; qs < 2; qs++)
#pragma unroll
        for (int reg = 0; reg < 4; reg++) {
            const float inv = 1.0f / lsum[qs][reg];
            const int srow = qb + qs * 16 + q4 * 4 + reg;
            _Float16* Xrow = Xh + (size_t)(b * S_LEN + srow) * 1024 + h * DK;
#pragma unroll
            for (int nt = 0; nt < 4; nt++)
                Xrow[nt * 16 + l15] = (_Float16)(O[qs][nt][reg] * inv);
        }
}

// ---------------------------------------------------------------------------
extern "C" void kernel_launch(void* const* d_in, const int* in_sizes, int n_in,
                              void* d_out, int out_size, void* d_ws, size_t ws_size,
                              hipStream_t stream) {
    const float* q  = (const float*)d_in[0];
    const float* k  = (const float*)d_in[1];
    const float* v  = (const float*)d_in[2];
    const int* mask = (const int*)d_in[3];
    const float* wq = (const float*)d_in[4];
    const float* bq = (const float*)d_in[5];
    const float* wk = (const float*)d_in[6];
    const float* bk = (const float*)d_in[7];
    const float* wv = (const float*)d_in[8];
    const float* bv = (const float*)d_in[9];
    const float* wo = (const float*)d_in[10];
    const float* bo = (const float*)d_in[11];
    float* out = (float*)d_out;

    char* ws = (char*)d_ws;
    const size_t MB = 1u << 20;
    _Float16* Wh   = (_Float16*)ws;                    // 4 x 2 MB (wq,wk,wv,wo)
    _Float16* Ah   = (_Float16*)(ws + 8 * MB);         // 3 x 8 MB (q,k,v fp16)
    _Float16* QKVh = (_Float16*)(ws + 32 * MB);        // 3 x 8 MB head-major
    _Float16* Vt   = (_Float16*)(ws + 56 * MB);        // 8 MB
    unsigned long long* mb = (unsigned long long*)(ws + 64 * MB);  // 512 KB
    _Float16* Xh   = Ah;                               // reuse q slot (8 MB)

    cast_h<<<dim3(1024, 4), 256, 0, stream>>>(wq, wk, wv, wo, Wh, 1024);
    cast_h<<<dim3(4096, 3), 256, 0, stream>>>(q, k, v, nullptr, Ah, M_ROWS);

    gemm_f16<1><<<dim3(8, 32, 3), 256, 0, stream>>>(Ah, Wh, bq, bk, bv, QKVh);

    vt_trans<<<dim3(32, 32), 256, 0, stream>>>(
        (const short*)(QKVh + (size_t)2 * M_ROWS * 1024), (short*)Vt);
    mask_pack<<<S_LEN * (S_LEN / 64) / 4, 256, 0, stream>>>(mask, mb);

    attn_mfma<<<dim3(16, 32), 256, 0, stream>>>(QKVh, QKVh + (size_t)M_ROWS * 1024,
                                                Vt, mb, Xh);

    gemm_f16<0><<<dim3(8, 32, 1), 256, 0, stream>>>(Xh, Wh + (size_t)3 * 1024 * 1024,
                                                    bo, bo, bo, out);
}

// Round 7
// 292.764 us; speedup vs baseline: 1.3162x; 1.3162x over previous
//
#include <hip/hip_runtime.h>
#include <hip/hip_bf16.h>

#define D_MODEL 1024
#define NH 16
#define DK 64
#define S_LEN 2048
#define BATCH 2
#define M_ROWS (BATCH * S_LEN)   // 4096

typedef float    floatx4 __attribute__((ext_vector_type(4)));
typedef _Float16 half8   __attribute__((ext_vector_type(8)));
typedef _Float16 half4v  __attribute__((ext_vector_type(4)));

#define LOG2E 1.4426950408889634f

__device__ __forceinline__ half8 ldh8(const _Float16* p) {
    return __builtin_bit_cast(half8, *(const uint4*)p);
}
__device__ __forceinline__ void gld16(const void* g, void* l) {
    __builtin_amdgcn_global_load_lds(
        (const __attribute__((address_space(1))) void*)g,
        (__attribute__((address_space(3))) void*)l, 16, 0, 0);
}
// swap lanes 0<->1, 2<->3 within each quad (DPP quad_perm(1,0,3,2))
__device__ __forceinline__ float dpp_swap1(float x) {
    return __builtin_bit_cast(float,
        __builtin_amdgcn_mov_dpp(__builtin_bit_cast(int, x), 0xB1, 0xF, 0xF, false));
}

// ---------------------------------------------------------------------------
// fp32 [R][1024] -> fp16 [R][1024].  grid (R, Z); Z selects src / dst slice.
// ---------------------------------------------------------------------------
__global__ __launch_bounds__(256)
void cast_h(const float* __restrict__ s0, const float* __restrict__ s1,
            const float* __restrict__ s2, const float* __restrict__ s3,
            _Float16* __restrict__ out, int R) {
    const int z = blockIdx.y;
    const float* src = (z == 0) ? s0 : (z == 1) ? s1 : (z == 2) ? s2 : s3;
    const size_t idx = ((size_t)blockIdx.x * 256 + threadIdx.x) * 4;
    float4 v = *(const float4*)&src[idx];
    half4v h = {(_Float16)v.x, (_Float16)v.y, (_Float16)v.z, (_Float16)v.w};
    *(half4v*)&out[(size_t)z * R * 1024 + idx] = h;
}

// ---------------------------------------------------------------------------
// C = A[M,1024] @ W[1024,1024]^T (+bias), fp16 MFMA.  (validated round 4)
// OUTMODE 0: fp32 row-major.  OUTMODE 1: fp16 head-major, z selects problem;
// z==0 (Q) scaled by 0.125*log2e (exp2-folding for attention).
// ---------------------------------------------------------------------------
template <int OUTMODE>
__global__ __launch_bounds__(256)
void gemm_f16(const _Float16* __restrict__ Abase, const _Float16* __restrict__ Wbase,
              const float* __restrict__ b0, const float* __restrict__ b1,
              const float* __restrict__ b2, void* __restrict__ Obase) {
    __shared__ __align__(16) _Float16 As[128 * 64];
    __shared__ __align__(16) _Float16 Ws[128 * 64];
    const int tid = threadIdx.x;
    const int w = tid >> 6, lane = tid & 63;
    const int l15 = lane & 15, q4 = lane >> 4;
    const int z = (OUTMODE == 1) ? blockIdx.z : 0;
    const int m0 = blockIdx.y * 128, n0 = blockIdx.x * 128;
    const int wm = w >> 1, wn = w & 1;

    const _Float16* A = Abase + (size_t)z * M_ROWS * 1024;
    const _Float16* W = Wbase + (size_t)z * 1024 * 1024;
    const float* bias = (OUTMODE == 1) ? ((z == 0) ? b0 : (z == 1) ? b1 : b2) : b0;

    int srow[4], sseg[4];
#pragma unroll
    for (int i = 0; i < 4; i++) {
        const int slot = i * 256 + tid;
        srow[i] = slot >> 3;
        sseg[i] = ((slot & 7) ^ (srow[i] & 7)) * 8;
    }

    int aoff[4][2], woff[4][2];
#pragma unroll
    for (int r = 0; r < 4; r++) {
        const int ar = wm * 64 + r * 16 + l15;
        const int wr = wn * 64 + r * 16 + l15;
#pragma unroll
        for (int kc = 0; kc < 2; kc++) {
            aoff[r][kc] = (ar * 8 + ((kc * 4 + q4) ^ (ar & 7))) * 8;
            woff[r][kc] = (wr * 8 + ((kc * 4 + q4) ^ (wr & 7))) * 8;
        }
    }

    floatx4 acc[4][4];
#pragma unroll
    for (int r = 0; r < 4; r++)
#pragma unroll
        for (int c = 0; c < 4; c++) acc[r][c] = (floatx4){0.f, 0.f, 0.f, 0.f};

    for (int k0 = 0; k0 < 1024; k0 += 64) {
#pragma unroll
        for (int i = 0; i < 4; i++) {
            const int lb = (i * 256 + w * 64) * 8;
            gld16(&A[(size_t)(m0 + srow[i]) * 1024 + k0 + sseg[i]], &As[lb]);
            gld16(&W[(size_t)(n0 + srow[i]) * 1024 + k0 + sseg[i]], &Ws[lb]);
        }
        __syncthreads();

        half8 af[4][2], wf[4][2];
#pragma unroll
        for (int r = 0; r < 4; r++)
#pragma unroll
            for (int kc = 0; kc < 2; kc++) {
                af[r][kc] = ldh8(&As[aoff[r][kc]]);
                wf[r][kc] = ldh8(&Ws[woff[r][kc]]);
            }
#pragma unroll
        for (int kc = 0; kc < 2; kc++)
#pragma unroll
            for (int r = 0; r < 4; r++)
#pragma unroll
                for (int c = 0; c < 4; c++)
                    acc[r][c] = __builtin_amdgcn_mfma_f32_16x16x32_f16(
                        af[r][kc], wf[c][kc], acc[r][c], 0, 0, 0);
        __syncthreads();
    }

#pragma unroll
    for (int r = 0; r < 4; r++)
#pragma unroll
        for (int c = 0; c < 4; c++)
#pragma unroll
            for (int reg = 0; reg < 4; reg++) {
                const int m = m0 + wm * 64 + r * 16 + q4 * 4 + reg;
                const int n = n0 + wn * 64 + c * 16 + l15;
                float val = acc[r][c][reg] + bias[n];
                if (OUTMODE == 0) {
                    ((float*)Obase)[(size_t)m * 1024 + n] = val;
                } else {
                    if (z == 0) val *= 0.125f * LOG2E;   // 1/sqrt(dk) * log2e
                    const int b = m >> 11, s = m & 2047;
                    const int h = n >> 6, d = n & 63;
                    _Float16* Oz = (_Float16*)Obase + (size_t)z * M_ROWS * 1024;
                    Oz[(((size_t)(b * 16 + h) * S_LEN + s) << 6) + d] = (_Float16)val;
                }
            }
}

// ---------------------------------------------------------------------------
// Vh fp16 [bh][s][64] -> Vt fp16 [bh][d][s]
// ---------------------------------------------------------------------------
__global__ __launch_bounds__(256)
void vt_trans(const short* __restrict__ Vh, short* __restrict__ Vt) {
    __shared__ __align__(16) short T[64][80];
    const int bh = blockIdx.y;
    const int s0 = blockIdx.x * 64;
    const int t = threadIdx.x;
#pragma unroll
    for (int i = 0; i < 2; i++) {
        const int p = t + i * 256, r = p >> 3, c8 = (p & 7) * 8;
        uint4 raw = *(const uint4*)&Vh[((size_t)bh * S_LEN + s0 + r) * 64 + c8];
        const short* sv = (const short*)&raw;
#pragma unroll
        for (int j = 0; j < 8; j++) T[c8 + j][r] = sv[j];
    }
    __syncthreads();
#pragma unroll
    for (int i = 0; i < 2; i++) {
        const int p = t + i * 256, d = p >> 3, seg = (p & 7) * 8;
        *(uint4*)&Vt[((size_t)bh * DK + d) * S_LEN + s0 + seg] =
            *(const uint4*)&T[d][seg];
    }
}

// ---------------------------------------------------------------------------
// mask int32 [S,S] -> bitmask uint64 mb[row][wid]
// ---------------------------------------------------------------------------
__global__ __launch_bounds__(256)
void mask_pack(const int* __restrict__ mask, unsigned long long* __restrict__ mb) {
    const int gw = blockIdx.x * 4 + (threadIdx.x >> 6);
    const int lane = threadIdx.x & 63;
    const int row = gw >> 5, wid = gw & 31;
    const int mv = mask[(size_t)row * S_LEN + wid * 64 + lane];
    unsigned long long bal = __ballot(mv != 0);
    if (lane == 0) mb[gw] = bal;
}

// ---------------------------------------------------------------------------
// MFMA flash attention v3: staged K/V (async gld16, XOR-swizzled, unpadded)
// + 32 q-rows/wave (2 subtiles share every K/V fragment read)
// + DPP-packed conflict-free P writes + exp2-folded scores.
// Grid (S/128, B*H), 256 threads = 4 waves.  LDS 34.8 KB.
// ---------------------------------------------------------------------------
__global__ __launch_bounds__(256)
void attn_mfma(const _Float16* __restrict__ Qh, const _Float16* __restrict__ Kh,
               const _Float16* __restrict__ Vt, const unsigned long long* __restrict__ mb,
               _Float16* __restrict__ Xh) {
    __shared__ __align__(16) _Float16 Ks[64 * 64];      // [key][d]  swizzled, 8 KB
    __shared__ __align__(16) _Float16 Vs[64 * 64];      // [d][key]  swizzled, 8 KB
    __shared__ __align__(16) _Float16 Ps[4][32 * 72];   // per-wave P, 18.4 KB

    const int tid = threadIdx.x;
    const int w = tid >> 6, lane = tid & 63;
    const int l15 = lane & 15, q4 = lane >> 4;
    const int bh = blockIdx.y, b = bh >> 4, h = bh & 15;
    const int qb = blockIdx.x * 128 + w * 32;

    const _Float16* Qg = Qh + ((size_t)bh * S_LEN + qb) * DK;
    const _Float16* Kg = Kh + (size_t)bh * S_LEN * DK;
    const _Float16* Vg = Vt + (size_t)bh * DK * S_LEN;

    // Q fragments (A-operand), resident all kernel (scale pre-folded in gemm)
    half8 Aq[2][2];
#pragma unroll
    for (int qs = 0; qs < 2; qs++)
#pragma unroll
        for (int ch = 0; ch < 2; ch++)
            Aq[qs][ch] = ldh8(&Qg[(qs * 16 + l15) * DK + ch * 32 + q4 * 8]);

    // staging slots (slot = i*256+tid): row = slot>>3, stored seg = slot&7,
    // global seg = (slot&7) ^ (row&7)  -> coalesced within each 128 B row
    int grow[2], gseg[2];
#pragma unroll
    for (int i = 0; i < 2; i++) {
        const int slot = i * 256 + tid;
        grow[i] = slot >> 3;
        gseg[i] = ((slot & 7) ^ (grow[i] & 7)) * 8;
    }

    // fragment offsets (halfs) into swizzled Ks/Vs — shared by K and V reads
    int foff[4][2];
#pragma unroll
    for (int t4 = 0; t4 < 4; t4++)
#pragma unroll
        for (int ch = 0; ch < 2; ch++)
            foff[t4][ch] = (t4 * 16 + l15) * 64 + (((ch * 4 + q4) ^ (l15 & 7)) * 8);

    // mask word row bases
    int mrow[2][4];
#pragma unroll
    for (int qs = 0; qs < 2; qs++)
#pragma unroll
        for (int reg = 0; reg < 4; reg++)
            mrow[qs][reg] = (qb + qs * 16 + q4 * 4 + reg) * (S_LEN / 64);

    floatx4 O[2][4];
#pragma unroll
    for (int qs = 0; qs < 2; qs++)
#pragma unroll
        for (int nt = 0; nt < 4; nt++) O[qs][nt] = (floatx4){0.f, 0.f, 0.f, 0.f};
    float lsum[2][4] = {{0.f, 0.f, 0.f, 0.f}, {0.f, 0.f, 0.f, 0.f}};

    const bool evenlane = ((lane & 1) == 0);

    for (int j0 = 0; j0 < S_LEN; j0 += 64) {
        // async stage K tile [64 key][64 d] and V^T tile [64 d][64 key]
#pragma unroll
        for (int i = 0; i < 2; i++) {
            const int lb = (i * 256 + w * 64) * 8;     // wave-uniform base (halfs)
            gld16(&Kg[(size_t)(j0 + grow[i]) * DK + gseg[i]], &Ks[lb]);
            gld16(&Vg[(size_t)grow[i] * S_LEN + j0 + gseg[i]], &Vs[lb]);
        }
        const int jw = j0 >> 6;
        unsigned long long mw[2][4];
#pragma unroll
        for (int qs = 0; qs < 2; qs++)
#pragma unroll
            for (int reg = 0; reg < 4; reg++)
                mw[qs][reg] = mb[mrow[qs][reg] + jw];
        __syncthreads();

        // K fragments once — reused by both q subtiles
        half8 Kf[4][2];
#pragma unroll
        for (int jt = 0; jt < 4; jt++)
#pragma unroll
            for (int ch = 0; ch < 2; ch++)
                Kf[jt][ch] = ldh8(&Ks[foff[jt][ch]]);

#pragma unroll
        for (int qs = 0; qs < 2; qs++) {
            // S tile: lane holds S[q=q4*4+reg][key=jt*16+l15] (exp2 domain)
            floatx4 Sf[4];
#pragma unroll
            for (int jt = 0; jt < 4; jt++) {
                floatx4 c = (floatx4){0.f, 0.f, 0.f, 0.f};
                c = __builtin_amdgcn_mfma_f32_16x16x32_f16(Aq[qs][0], Kf[jt][0], c, 0, 0, 0);
                c = __builtin_amdgcn_mfma_f32_16x16x32_f16(Aq[qs][1], Kf[jt][1], c, 0, 0, 0);
                Sf[jt] = c;
            }
            // soft mask (-1 -> -log2e), exp2, DPP pair-pack, b32 LDS write
#pragma unroll
            for (int reg = 0; reg < 4; reg++) {
                const unsigned long long m = mw[qs][reg];
#pragma unroll
                for (int jt = 0; jt < 4; jt++) {
                    float s = Sf[jt][reg];
                    s = ((m >> (jt * 16 + l15)) & 1ull) ? s : -LOG2E;
                    const float p = __builtin_amdgcn_exp2f(s);
                    lsum[qs][reg] += p;
                    const float po = dpp_swap1(p);
                    if (evenlane) {
                        *(unsigned*)&Ps[w][(qs * 16 + q4 * 4 + reg) * 72 +
                                           jt * 16 + l15] =
                            __builtin_bit_cast(unsigned,
                                __builtin_amdgcn_cvt_pkrtz(p, po));
                    }
                }
            }
        }

        // PV: O[qs] += P[qs] @ V  (same-wave LDS write->read; V frags shared)
#pragma unroll
        for (int qs = 0; qs < 2; qs++) {
            half8 Ap[2];
#pragma unroll
            for (int ch = 0; ch < 2; ch++)
                Ap[ch] = ldh8(&Ps[w][(qs * 16 + l15) * 72 + ch * 32 + q4 * 8]);
#pragma unroll
            for (int nt = 0; nt < 4; nt++) {
                O[qs][nt] = __builtin_amdgcn_mfma_f32_16x16x32_f16(
                    Ap[0], ldh8(&Vs[foff[nt][0]]), O[qs][nt], 0, 0, 0);
                O[qs][nt] = __builtin_amdgcn_mfma_f32_16x16x32_f16(
                    Ap[1], ldh8(&Vs[foff[nt][1]]), O[qs][nt], 0, 0, 0);
            }
        }
        __syncthreads();
    }

    // reduce row sums over the 16 key-lanes, normalize, store fp16 X
#pragma unroll
    for (int qs = 0; qs < 2; qs++)
#pragma unroll
        for (int reg = 0; reg < 4; reg++) {
#pragma unroll
            for (int off = 1; off < 16; off <<= 1)
                lsum[qs][reg] += __shfl_xor(lsum[qs][reg], off, 64);
        }
#pragma unroll
    for (int qs = 0; qs < 2; qs++)
#pragma unroll
        for (int reg = 0; reg < 4; reg++) {
            const float inv = 1.0f / lsum[qs][reg];
            const int srow = qb + qs * 16 + q4 * 4 + reg;
            _Float16* Xrow = Xh + (size_t)(b * S_LEN + srow) * 1024 + h * DK;
#pragma unroll
            for (int nt = 0; nt < 4; nt++)
                Xrow[nt * 16 + l15] = (_Float16)(O[qs][nt][reg] * inv);
        }
}

// ---------------------------------------------------------------------------
extern "C" void kernel_launch(void* const* d_in, const int* in_sizes, int n_in,
                              void* d_out, int out_size, void* d_ws, size_t ws_size,
                              hipStream_t stream) {
    const float* q  = (const float*)d_in[0];
    const float* k  = (const float*)d_in[1];
    const float* v  = (const float*)d_in[2];
    const int* mask = (const int*)d_in[3];
    const float* wq = (const float*)d_in[4];
    const float* bq = (const float*)d_in[5];
    const float* wk = (const float*)d_in[6];
    const float* bk = (const float*)d_in[7];
    const float* wv = (const float*)d_in[8];
    const float* bv = (const float*)d_in[9];
    const float* wo = (const float*)d_in[10];
    const float* bo = (const float*)d_in[11];
    float* out = (float*)d_out;

    char* ws = (char*)d_ws;
    const size_t MB = 1u << 20;
    _Float16* Wh   = (_Float16*)ws;                    // 4 x 2 MB (wq,wk,wv,wo)
    _Float16* Ah   = (_Float16*)(ws + 8 * MB);         // 3 x 8 MB (q,k,v fp16)
    _Float16* QKVh = (_Float16*)(ws + 32 * MB);        // 3 x 8 MB head-major
    _Float16* Vt   = (_Float16*)(ws + 56 * MB);        // 8 MB
    unsigned long long* mb = (unsigned long long*)(ws + 64 * MB);  // 512 KB
    _Float16* Xh   = Ah;                               // reuse q slot (8 MB)

    cast_h<<<dim3(1024, 4), 256, 0, stream>>>(wq, wk, wv, wo, Wh, 1024);
    cast_h<<<dim3(4096, 3), 256, 0, stream>>>(q, k, v, nullptr, Ah, M_ROWS);

    gemm_f16<1><<<dim3(8, 32, 3), 256, 0, stream>>>(Ah, Wh, bq, bk, bv, QKVh);

    vt_trans<<<dim3(32, 32), 256, 0, stream>>>(
        (const short*)(QKVh + (size_t)2 * M_ROWS * 1024), (short*)Vt);
    mask_pack<<<S_LEN * (S_LEN / 64) / 4, 256, 0, stream>>>(mask, mb);

    attn_mfma<<<dim3(16, 32), 256, 0, stream>>>(QKVh, QKVh + (size_t)M_ROWS * 1024,
                                                Vt, mb, Xh);

    gemm_f16<0><<<dim3(8, 32, 1), 256, 0, stream>>>(Xh, Wh + (size_t)3 * 1024 * 1024,
                                                    bo, bo, bo, out);
}